// Round 21
// baseline (55.306 us; speedup 1.0000x reference)
//
#include <hip/hip_runtime.h>
#include <hip/hip_bf16.h>

// TritonDynamicAttention: blocksparse causal attention, B=2,H=16,S=2048,D=64, BLOCK=32.
// R21: quad-share LDS staging. WG = 4 waves owning q-tiles {p, 31-p, 32+p, 63-p}
// (constant 130 steps/WG). Per kb the WG stages the 8KB packed K+V frag tile into
// LDS ONCE (register-staged, issue-early/write-late, double-buffered, 1 barrier/iter);
// all 4 waves read frags from LDS -> L2 operand traffic halves (the largest k_attn
// term). No kv-split => no merge pass; each wave writes its tile directly.
// Keeps: R17 fragment-packed layouts + fused prep, fp16 carrier, permlane32_swap,
// exp2 softmax w/ log2e-folded Q, defer-max, cvt_pkrtz, early-exit block mask.

typedef _Float16 f16_t;
typedef f16_t  f16x8  __attribute__((ext_vector_type(8)));
typedef __fp16 fp16x2 __attribute__((ext_vector_type(2)));
typedef float  f32x4  __attribute__((ext_vector_type(4)));
typedef float  f32x16 __attribute__((ext_vector_type(16)));
typedef int    i32x4  __attribute__((ext_vector_type(4)));
typedef int    i32x2  __attribute__((ext_vector_type(2)));
typedef unsigned int u32x4 __attribute__((ext_vector_type(4)));

constexpr int Bc = 2, Hc = 16, Sc = 2048, Dc = 64;
constexpr int NB = Sc / 32;                              // 64 mask blocks per side
constexpr float LOG2E = 1.4426950408889634f;
// per-bh fragment array: 64 kb * 4 frags * 64 lanes * 8 f16 = 131072 f16 (256 KiB)
constexpr size_t FRAG_BH = (size_t)NB * 4 * 64 * 8;

__device__ inline f32x16 mfma32(f16x8 a, f16x8 b, f32x16 c) {
    return __builtin_amdgcn_mfma_f32_32x32x16_f16(a, b, c, 0, 0, 0);
}
__device__ inline float fexp2(float x) { return __builtin_amdgcn_exp2f(x); }

union UB { u32x4 u; f16x8 v; };
union PK { fp16x2 h; unsigned int u; };

#if __has_builtin(__builtin_amdgcn_permlane32_swap)
#define HAVE_PLSWAP 1
__device__ inline i32x2 plswap(unsigned int a, unsigned int b) {
    return __builtin_amdgcn_permlane32_swap((int)a, (int)b, false, false);
}
__device__ inline float xhalf_max(float x) {
    i32x2 s = plswap((unsigned int)__float_as_int(x), (unsigned int)__float_as_int(x));
    return fmaxf(__int_as_float(s[0]), __int_as_float(s[1]));
}
__device__ inline float xhalf_sum(float x) {
    i32x2 s = plswap((unsigned int)__float_as_int(x), (unsigned int)__float_as_int(x));
    return __int_as_float(s[0]) + __int_as_float(s[1]);
}
#else
#define HAVE_PLSWAP 0
__device__ inline float xhalf_max(float x) { return fmaxf(x, __shfl_xor(x, 32)); }
__device__ inline float xhalf_sum(float x) { return x + __shfl_xor(x, 32); }
#endif

// ---------- fused prep (identical to R17) ----------
// [0,2048): K fragment-pack | [2048,4096): V fragment-pack | [4096,5120): blockmask
__global__ __launch_bounds__(256) void k_prep(const float* __restrict__ K,
                                              const float* __restrict__ V,
                                              const int* __restrict__ mask,
                                              const float* __restrict__ bias,
                                              f16_t* __restrict__ khf,
                                              f16_t* __restrict__ vaf,
                                              unsigned char* __restrict__ bm) {
    __shared__ f16_t tile[32 * 66];
    const int bid = blockIdx.x;
    const int t   = threadIdx.x;
    if (bid < 2048) {
        const int bh = bid >> 6, kb = bid & 63;
        const float* src = K + ((size_t)bh * Sc + (size_t)kb * 32) * Dc;
        {
            int r = t >> 3, c8 = (t & 7) * 8;
            f32x4 a = *(const f32x4*)(src + r * Dc + c8);
            f32x4 b = *(const f32x4*)(src + r * Dc + c8 + 4);
            float xs[8] = {a[0], a[1], a[2], a[3], b[0], b[1], b[2], b[3]};
#pragma unroll
            for (int j = 0; j < 8; j++) tile[r * 66 + c8 + j] = (f16_t)xs[j];
        }
        __syncthreads();
        {
            int kc = t >> 6, lane = t & 63, l31 = lane & 31, hi2 = (lane >> 5) & 1;
            f16x8 frag;
#pragma unroll
            for (int j = 0; j < 8; j++)
                frag[j] = tile[l31 * 66 + kc * 16 + hi2 * 8 + j];
            *(f16x8*)(khf + (((size_t)(bh * NB + kb) * 4 + kc) * 64 + lane) * 8) = frag;
        }
    } else if (bid < 4096) {
        const int b2 = bid - 2048;
        const int bh = b2 >> 6, kb = b2 & 63;
        const float* src = V + ((size_t)bh * Sc + (size_t)kb * 32) * Dc;
        {
            int r = t >> 3, c8 = (t & 7) * 8;
            f32x4 a = *(const f32x4*)(src + r * Dc + c8);
            f32x4 b = *(const f32x4*)(src + r * Dc + c8 + 4);
            float xs[8] = {a[0], a[1], a[2], a[3], b[0], b[1], b[2], b[3]};
#pragma unroll
            for (int j = 0; j < 8; j++) tile[r * 66 + c8 + j] = (f16_t)xs[j];
        }
        __syncthreads();
        {
            int f = t >> 6, lane = t & 63, l31 = lane & 31, hi2 = (lane >> 5) & 1;
            int tt = f >> 1, c = f & 1;
            f16x8 frag;
#pragma unroll
            for (int j = 0; j < 8; j++)
                frag[j] = tile[(c * 16 + hi2 * 8 + j) * 66 + tt * 32 + l31];
            *(f16x8*)(vaf + (((size_t)(bh * NB + kb) * 4 + f) * 64 + lane) * 8) = frag;
        }
    } else {
        const int b3 = bid - 4096;
        const int h  = b3 >> 6;
        const int br = b3 & 63;
        float bv = bias[h];
        unsigned char* outp = bm + ((size_t)h * NB + br) * NB;
        if (bv > 0.f) {
            if (t < NB) outp[t] = 1;
            return;
        }
        int bc0 = t >> 3;
        int bc1 = 32 + bc0;
        const int* base = mask + ((size_t)h * Sc + (size_t)br * 32) * (size_t)Sc;
        const int* p0 = base + 4 * t;
        const int* p1 = base + 1024 + 4 * t;
        bool d0 = (bc0 <= br), d1 = (bc1 <= br);
        int acc0 = 0, acc1 = 0;
        if (d0) {
#pragma unroll
            for (int r = 0; r < 4; r++) {
                i32x4 vv = *(const i32x4*)(p0 + (size_t)r * Sc);
                acc0 += vv[0] + vv[1] + vv[2] + vv[3];
            }
        }
        if (d1) {
#pragma unroll
            for (int r = 0; r < 4; r++) {
                i32x4 vv = *(const i32x4*)(p1 + (size_t)r * Sc);
                acc1 += vv[0] + vv[1] + vv[2] + vv[3];
            }
        }
        int g0 = acc0, g1 = acc1;
#pragma unroll
        for (int off = 1; off < 8; off <<= 1) {
            g0 += __shfl_xor(g0, off);
            g1 += __shfl_xor(g1, off);
        }
        bool act0 = (float)g0 + bv > 0.f;
        bool act1 = (float)g1 + bv > 0.f;
        if (d0 && !act0) {
            for (int r = 4; r < 32; r++) {
                i32x4 vv = *(const i32x4*)(p0 + (size_t)r * Sc);
                acc0 += vv[0] + vv[1] + vv[2] + vv[3];
            }
            int s = acc0;
#pragma unroll
            for (int off = 1; off < 8; off <<= 1) s += __shfl_xor(s, off);
            act0 = (float)s + bv > 0.f;
        }
        if (d1 && !act1) {
            for (int r = 4; r < 32; r++) {
                i32x4 vv = *(const i32x4*)(p1 + (size_t)r * Sc);
                acc1 += vv[0] + vv[1] + vv[2] + vv[3];
            }
            int s = acc1;
#pragma unroll
            for (int off = 1; off < 8; off <<= 1) s += __shfl_xor(s, off);
            act1 = (float)s + bv > 0.f;
        }
        if ((t & 7) == 0) {
            if (d0) outp[bc0] = act0 ? 1 : 0;
            if (d1) outp[bc1] = act1 ? 1 : 0;
        }
    }
}

// ---------- flash blocksparse causal attention: quad-share LDS staging ----------
#if HAVE_PLSWAP
#define EXCHANGE_P(PB, B0, B1) do {                                            \
        i32x2 e0_ = plswap(PB[0], PB[2]);                                      \
        i32x2 e1_ = plswap(PB[1], PB[3]);                                      \
        i32x2 e2_ = plswap(PB[4], PB[6]);                                      \
        i32x2 e3_ = plswap(PB[5], PB[7]);                                      \
        B0.u[0] = (unsigned int)e0_[0]; B0.u[1] = (unsigned int)e1_[0];        \
        B0.u[2] = (unsigned int)e0_[1]; B0.u[3] = (unsigned int)e1_[1];        \
        B1.u[0] = (unsigned int)e2_[0]; B1.u[1] = (unsigned int)e3_[0];        \
        B1.u[2] = (unsigned int)e2_[1]; B1.u[3] = (unsigned int)e3_[1];        \
} while (0)
#else
#define EXCHANGE_P(PB, B0, B1) do {                                            \
        unsigned int qb_[8];                                                   \
        _Pragma("unroll")                                                      \
        for (int i_ = 0; i_ < 8; i_++)                                         \
            qb_[i_] = (unsigned int)__shfl_xor((int)PB[i_], 32);               \
        B0.u[0] = hi ? qb_[2] : PB[0]; B0.u[1] = hi ? qb_[3] : PB[1];          \
        B0.u[2] = hi ? PB[2] : qb_[0]; B0.u[3] = hi ? PB[3] : qb_[1];          \
        B1.u[0] = hi ? qb_[6] : PB[4]; B1.u[1] = hi ? qb_[7] : PB[5];          \
        B1.u[2] = hi ? PB[6] : qb_[4]; B1.u[3] = hi ? PB[7] : qb_[5];          \
} while (0)
#endif

// one tile-chain update; operands from LDS-staged fragment tile (sk/sv)
#define CORE(OT0, OT1, MR, LR, QH, BROW, kb_, SK, SV) do {                     \
        f16x8 kbuf_[4];                                                        \
        _Pragma("unroll")                                                      \
        for (int kc_ = 0; kc_ < 4; kc_++)                                      \
            kbuf_[kc_] = *(const f16x8*)((SK) + kc_ * 512 + lane * 8);         \
        f16x8 va_[2][2];                                                       \
        _Pragma("unroll")                                                      \
        for (int t_ = 0; t_ < 2; t_++)                                         \
            _Pragma("unroll")                                                  \
            for (int c_ = 0; c_ < 2; c_++)                                     \
                va_[t_][c_] = *(const f16x8*)((SV) + (t_ * 2 + c_) * 512 + lane * 8); \
        f32x16 st;                                                             \
        _Pragma("unroll")                                                      \
        for (int r_ = 0; r_ < 16; r_++) st[r_] = 0.f;                          \
        _Pragma("unroll")                                                      \
        for (int kc_ = 0; kc_ < 4; kc_++)                                      \
            st = mfma32(kbuf_[kc_], QH[kc_], st);                              \
        if ((kb_) == (BROW)) {                                                 \
            _Pragma("unroll")                                                  \
            for (int r_ = 0; r_ < 16; r_++) {                                  \
                int kvl_ = (r_ & 3) + 8 * (r_ >> 2) + 4 * hi;                  \
                if (kvl_ > l31) st[r_] = -1e30f;                               \
            }                                                                  \
        }                                                                      \
        float a0_ = fmaxf(fmaxf(st[0], st[1]), st[2]);                         \
        float a1_ = fmaxf(fmaxf(st[3], st[4]), st[5]);                         \
        float a2_ = fmaxf(fmaxf(st[6], st[7]), st[8]);                         \
        float a3_ = fmaxf(fmaxf(st[9], st[10]), st[11]);                       \
        float a4_ = fmaxf(fmaxf(st[12], st[13]), st[14]);                      \
        float b0m_ = fmaxf(fmaxf(a0_, a1_), a2_);                              \
        float b1m_ = fmaxf(fmaxf(a3_, a4_), st[15]);                           \
        float mx_ = xhalf_max(fmaxf(b0m_, b1m_));                              \
        if (__ballot(mx_ > MR + 11.0f)) {                                      \
            float mn_ = fmaxf(MR, mx_);                                        \
            float al_ = fexp2(MR - mn_);                                       \
            MR = mn_;                                                          \
            LR *= al_;                                                         \
            OT0 *= al_; OT1 *= al_;                                            \
        }                                                                      \
        _Pragma("unroll")                                                      \
        for (int r_ = 0; r_ < 16; r_++) st[r_] = fexp2(st[r_] - MR);           \
        {                                                                      \
            float s0 = (st[0] + st[1]) + (st[2] + st[3]);                      \
            float s1 = (st[4] + st[5]) + (st[6] + st[7]);                      \
            float s2 = (st[8] + st[9]) + (st[10] + st[11]);                    \
            float s3 = (st[12] + st[13]) + (st[14] + st[15]);                  \
            LR += ((s0 + s1) + (s2 + s3));                                     \
        }                                                                      \
        unsigned int pb_[8];                                                   \
        _Pragma("unroll")                                                      \
        for (int i_ = 0; i_ < 8; i_++) {                                       \
            PK pk_;                                                            \
            pk_.h = __builtin_amdgcn_cvt_pkrtz(st[2 * i_], st[2 * i_ + 1]);    \
            pb_[i_] = pk_.u;                                                   \
        }                                                                      \
        UB b0_, b1_;                                                           \
        EXCHANGE_P(pb_, b0_, b1_);                                             \
        OT0 = mfma32(va_[0][0], b0_.v, OT0);                                   \
        OT0 = mfma32(va_[0][1], b1_.v, OT0);                                   \
        OT1 = mfma32(va_[1][0], b0_.v, OT1);                                   \
        OT1 = mfma32(va_[1][1], b1_.v, OT1);                                   \
} while (0)

#define QLOAD(QH, q0_) do {                                                    \
        const float* qr_ = q_ptr + (size_t)((q0_) + l31) * Dc + hi * 8;        \
        _Pragma("unroll")                                                      \
        for (int kc_ = 0; kc_ < 4; kc_++) {                                    \
            f32x4 a_ = *(const f32x4*)(qr_ + kc_ * 16);                        \
            f32x4 b_ = *(const f32x4*)(qr_ + kc_ * 16 + 4);                    \
            float xs_[8] = {a_[0], a_[1], a_[2], a_[3], b_[0], b_[1], b_[2], b_[3]}; \
            _Pragma("unroll")                                                  \
            for (int j_ = 0; j_ < 8; j_++) QH[kc_][j_] = (f16_t)(xs_[j_] * LOG2E); \
        }                                                                      \
} while (0)

// WG = 4 waves; wave w owns q-tile {p, 31-p, 32+p, 63-p}[w]; K/V staged via LDS.
__global__ __launch_bounds__(256, 2) void k_attn(const float* __restrict__ Q,
                                                 const f16_t* __restrict__ KHF,
                                                 const f16_t* __restrict__ VAF,
                                                 const unsigned char* __restrict__ BM,
                                                 float* __restrict__ Out) {
    __shared__ f16_t sbuf[2][4096];   // 2 x 8KB: [0..2048) K frags, [2048..4096) V frags

    const int p  = blockIdx.x >> 5;    // 0..15
    const int bh = blockIdx.x & 31;
    const int h  = bh & (Hc - 1);
    const int t  = threadIdx.x;
    const int w  = t >> 6;
    const int lane = t & 63;
    const int l31  = lane & 31, hi = lane >> 5;

    const size_t bh_off = (size_t)bh * Sc * Dc;
    const float* q_ptr  = Q + bh_off;
    const f16_t* khfp   = KHF + (size_t)bh * FRAG_BH;
    const f16_t* vafp   = VAF + (size_t)bh * FRAG_BH;

    const int qi = (w == 0) ? p : (w == 1) ? 31 - p : (w == 2) ? 32 + p : 63 - p;
    const int brow = qi;
    const int kend = 63 - p;           // max brow across the 4 waves
    const int q0   = qi * 32;
    const unsigned char* bmrow = BM + ((size_t)h * NB + brow) * NB;
    const unsigned long long actmask = __ballot(bmrow[lane] != 0);

    f16x8 qh[4];
    QLOAD(qh, q0);

    f32x16 ot0, ot1;
#pragma unroll
    for (int r = 0; r < 16; r++) { ot0[r] = 0.f; ot1[r] = 0.f; }
    float mrow = -INFINITY, lrow = 0.f;

    // staging: thread t copies 16B of K-tile and 16B of V-tile per kb (coalesced).
    // Issue-early/write-late: loads for kb+1 issued before the sync covering kb.
    f16x8 rK = *(const f16x8*)(khfp + (size_t)0 * 2048 + t * 8);
    f16x8 rV = *(const f16x8*)(vafp + (size_t)0 * 2048 + t * 8);
    for (int kb = 0; kb <= kend; kb++) {
        f16_t* sk = &sbuf[kb & 1][0];
        f16_t* sv = &sbuf[kb & 1][2048];
        *(f16x8*)(sk + t * 8) = rK;
        *(f16x8*)(sv - 2048 + 2048 + t * 8) = rV;   // sv + t*8
        if (kb < kend) {
            rK = *(const f16x8*)(khfp + (size_t)(kb + 1) * 2048 + t * 8);
            rV = *(const f16x8*)(vafp + (size_t)(kb + 1) * 2048 + t * 8);
        }
        __syncthreads();   // buf[kb&1] ready; also fences CORE(kb-1) before next write
        if (kb <= brow && ((actmask >> kb) & 1ull)) {
            CORE(ot0, ot1, mrow, lrow, qh, brow, kb, sk, sv);
        }
    }

    // epilogue: combine lane-half l partials, normalize, write directly (no merge)
    float lsum = xhalf_sum(lrow);
    float inv  = (lsum > 0.f) ? (1.f / lsum) : 0.f;
    float* op  = Out + bh_off + (size_t)(q0 + l31) * Dc;
#pragma unroll
    for (int g = 0; g < 4; g++) {
        f32x4 w0, w1;
#pragma unroll
        for (int jj = 0; jj < 4; jj++) {
            int r = g * 4 + jj;
            w0[jj] = ot0[r] * inv;
            w1[jj] = ot1[r] * inv;
        }
        *(f32x4*)(op + g * 8 + hi * 4)      = w0;
        *(f32x4*)(op + 32 + g * 8 + hi * 4) = w1;
    }
}

extern "C" void kernel_launch(void* const* d_in, const int* in_sizes, int n_in,
                              void* d_out, int out_size, void* d_ws, size_t ws_size,
                              hipStream_t stream) {
    const float* Q    = (const float*)d_in[0];
    const float* K    = (const float*)d_in[1];
    const float* V    = (const float*)d_in[2];
    const float* bias = (const float*)d_in[3];
    const int*   mask = (const int*)d_in[4];
    float* out = (float*)d_out;

    char* ws = (char*)d_ws;
    f16_t* khf = (f16_t*)ws;                                    // 8 MiB
    f16_t* vaf = (f16_t*)(ws + (size_t)32 * FRAG_BH * 2);       // 8 MiB
    unsigned char* bm = (unsigned char*)(ws + (size_t)64 * FRAG_BH * 2);  // 64 KiB

    k_prep <<<5120, 256, 0, stream>>>(K, V, mask, bias, khf, vaf, bm);
    k_attn <<<Hc * Bc * (NB / 4), 256, 0, stream>>>(Q, khf, vaf, bm, out);
}

// Round 22
// 46.575 us; speedup vs baseline: 1.1875x; 1.1875x over previous
//
#include <hip/hip_runtime.h>
#include <hip/hip_bf16.h>

// TritonDynamicAttention: blocksparse causal attention, B=2,H=16,S=2048,D=64, BLOCK=32.
// R22 = R17 verbatim (best measured: 46.7us). Terminal revert after 7 consecutive
// probes (ILP / prefetch x2 / TLP / chain-merge / setprio / LDS-staging) all neutral
// or regressions. k_attn is at a multi-pipe balance point (L2 ~11us, L1 ~7us, MFMA
// ~8us, VALU ~8us, ~570 TF effective); k_prep at its HBM roofline (~90MB fp32).
// Structure: fragment-packed coalesced K/V (k_prep writes operands in exact lane
// order -> every k_attn load is base+lane*16B), complementary-pair tiling (65
// steps/WG), kv-parity 2-wave split + exact LDS flash-decode merge, permlane32_swap
// cross-half exchange, exp2 softmax w/ log2e-folded Q, defer-max rescale skip,
// cvt_pkrtz packing, early-exit block mask.

typedef _Float16 f16_t;
typedef f16_t  f16x8  __attribute__((ext_vector_type(8)));
typedef __fp16 fp16x2 __attribute__((ext_vector_type(2)));
typedef float  f32x4  __attribute__((ext_vector_type(4)));
typedef float  f32x16 __attribute__((ext_vector_type(16)));
typedef int    i32x4  __attribute__((ext_vector_type(4)));
typedef int    i32x2  __attribute__((ext_vector_type(2)));
typedef unsigned int u32x4 __attribute__((ext_vector_type(4)));

constexpr int Bc = 2, Hc = 16, Sc = 2048, Dc = 64;
constexpr int NB = Sc / 32;                              // 64 mask blocks per side
constexpr float LOG2E = 1.4426950408889634f;
// per-bh fragment array: 64 kb * 4 frags * 64 lanes * 8 f16 = 131072 f16 (256 KiB)
constexpr size_t FRAG_BH = (size_t)NB * 4 * 64 * 8;

__device__ inline f32x16 mfma32(f16x8 a, f16x8 b, f32x16 c) {
    return __builtin_amdgcn_mfma_f32_32x32x16_f16(a, b, c, 0, 0, 0);
}
__device__ inline float fexp2(float x) { return __builtin_amdgcn_exp2f(x); }

union UB { u32x4 u; f16x8 v; };
union PK { fp16x2 h; unsigned int u; };

#if __has_builtin(__builtin_amdgcn_permlane32_swap)
#define HAVE_PLSWAP 1
__device__ inline i32x2 plswap(unsigned int a, unsigned int b) {
    return __builtin_amdgcn_permlane32_swap((int)a, (int)b, false, false);
}
__device__ inline float xhalf_max(float x) {
    i32x2 s = plswap((unsigned int)__float_as_int(x), (unsigned int)__float_as_int(x));
    return fmaxf(__int_as_float(s[0]), __int_as_float(s[1]));
}
__device__ inline float xhalf_sum(float x) {
    i32x2 s = plswap((unsigned int)__float_as_int(x), (unsigned int)__float_as_int(x));
    return __int_as_float(s[0]) + __int_as_float(s[1]);
}
#else
#define HAVE_PLSWAP 0
__device__ inline float xhalf_max(float x) { return fmaxf(x, __shfl_xor(x, 32)); }
__device__ inline float xhalf_sum(float x) { return x + __shfl_xor(x, 32); }
#endif

// ---------- fused prep ----------
// [0,2048): K fragment-pack | [2048,4096): V fragment-pack | [4096,5120): blockmask
__global__ __launch_bounds__(256) void k_prep(const float* __restrict__ K,
                                              const float* __restrict__ V,
                                              const int* __restrict__ mask,
                                              const float* __restrict__ bias,
                                              f16_t* __restrict__ khf,
                                              f16_t* __restrict__ vaf,
                                              unsigned char* __restrict__ bm) {
    __shared__ f16_t tile[32 * 66];
    const int bid = blockIdx.x;
    const int t   = threadIdx.x;
    if (bid < 2048) {
        // ---- K pack: block (bh, kb) = K[bh][kb*32 .. +32][0..64] ----
        const int bh = bid >> 6, kb = bid & 63;
        const float* src = K + ((size_t)bh * Sc + (size_t)kb * 32) * Dc;
        {
            int r = t >> 3, c8 = (t & 7) * 8;      // coalesced read: 8 f32/thread
            f32x4 a = *(const f32x4*)(src + r * Dc + c8);
            f32x4 b = *(const f32x4*)(src + r * Dc + c8 + 4);
            float xs[8] = {a[0], a[1], a[2], a[3], b[0], b[1], b[2], b[3]};
#pragma unroll
            for (int j = 0; j < 8; j++) tile[r * 66 + c8 + j] = (f16_t)xs[j];
        }
        __syncthreads();
        {
            int kc = t >> 6, lane = t & 63, l31 = lane & 31, hi2 = (lane >> 5) & 1;
            f16x8 frag;
#pragma unroll
            for (int j = 0; j < 8; j++)
                frag[j] = tile[l31 * 66 + kc * 16 + hi2 * 8 + j];
            *(f16x8*)(khf + (((size_t)(bh * NB + kb) * 4 + kc) * 64 + lane) * 8) = frag;
        }
    } else if (bid < 4096) {
        // ---- V pack: block (bh, kb) = V[bh][kb*32 .. +32][0..64], frag = V^T ----
        const int b2 = bid - 2048;
        const int bh = b2 >> 6, kb = b2 & 63;
        const float* src = V + ((size_t)bh * Sc + (size_t)kb * 32) * Dc;
        {
            int r = t >> 3, c8 = (t & 7) * 8;      // tile[s][d]
            f32x4 a = *(const f32x4*)(src + r * Dc + c8);
            f32x4 b = *(const f32x4*)(src + r * Dc + c8 + 4);
            float xs[8] = {a[0], a[1], a[2], a[3], b[0], b[1], b[2], b[3]};
#pragma unroll
            for (int j = 0; j < 8; j++) tile[r * 66 + c8 + j] = (f16_t)xs[j];
        }
        __syncthreads();
        {
            int f = t >> 6, lane = t & 63, l31 = lane & 31, hi2 = (lane >> 5) & 1;
            int tt = f >> 1, c = f & 1;
            f16x8 frag;                            // frag[j] = V[kb*32+c*16+hi*8+j][tt*32+l31]
#pragma unroll
            for (int j = 0; j < 8; j++)
                frag[j] = tile[(c * 16 + hi2 * 8 + j) * 66 + tt * 32 + l31];
            *(f16x8*)(vaf + (((size_t)(bh * NB + kb) * 4 + f) * 64 + lane) * 8) = frag;
        }
    } else {
        // ---- block mask with early-exit (mask values nonnegative -> partial sums
        // are monotone lower bounds; certify 'active' after 4/32 rows) ----
        const int b3 = bid - 4096;
        const int h  = b3 >> 6;
        const int br = b3 & 63;
        float bv = bias[h];
        unsigned char* outp = bm + ((size_t)h * NB + br) * NB;
        if (bv > 0.f) {
            if (t < NB) outp[t] = 1;
            return;
        }
        int bc0 = t >> 3;
        int bc1 = 32 + bc0;
        const int* base = mask + ((size_t)h * Sc + (size_t)br * 32) * (size_t)Sc;
        const int* p0 = base + 4 * t;
        const int* p1 = base + 1024 + 4 * t;
        bool d0 = (bc0 <= br), d1 = (bc1 <= br);
        int acc0 = 0, acc1 = 0;
        if (d0) {
#pragma unroll
            for (int r = 0; r < 4; r++) {
                i32x4 vv = *(const i32x4*)(p0 + (size_t)r * Sc);
                acc0 += vv[0] + vv[1] + vv[2] + vv[3];
            }
        }
        if (d1) {
#pragma unroll
            for (int r = 0; r < 4; r++) {
                i32x4 vv = *(const i32x4*)(p1 + (size_t)r * Sc);
                acc1 += vv[0] + vv[1] + vv[2] + vv[3];
            }
        }
        int g0 = acc0, g1 = acc1;
#pragma unroll
        for (int off = 1; off < 8; off <<= 1) {
            g0 += __shfl_xor(g0, off);
            g1 += __shfl_xor(g1, off);
        }
        bool act0 = (float)g0 + bv > 0.f;
        bool act1 = (float)g1 + bv > 0.f;
        if (d0 && !act0) {
            for (int r = 4; r < 32; r++) {
                i32x4 vv = *(const i32x4*)(p0 + (size_t)r * Sc);
                acc0 += vv[0] + vv[1] + vv[2] + vv[3];
            }
            int s = acc0;
#pragma unroll
            for (int off = 1; off < 8; off <<= 1) s += __shfl_xor(s, off);
            act0 = (float)s + bv > 0.f;
        }
        if (d1 && !act1) {
            for (int r = 4; r < 32; r++) {
                i32x4 vv = *(const i32x4*)(p1 + (size_t)r * Sc);
                acc1 += vv[0] + vv[1] + vv[2] + vv[3];
            }
            int s = acc1;
#pragma unroll
            for (int off = 1; off < 8; off <<= 1) s += __shfl_xor(s, off);
            act1 = (float)s + bv > 0.f;
        }
        if ((t & 7) == 0) {
            if (d0) outp[bc0] = act0 ? 1 : 0;
            if (d1) outp[bc1] = act1 ? 1 : 0;
        }
    }
}

// ---------- flash blocksparse causal attention: pairs + coalesced fragment loads -----
#if HAVE_PLSWAP
#define EXCHANGE_P(PB, B0, B1) do {                                            \
        i32x2 e0_ = plswap(PB[0], PB[2]);                                      \
        i32x2 e1_ = plswap(PB[1], PB[3]);                                      \
        i32x2 e2_ = plswap(PB[4], PB[6]);                                      \
        i32x2 e3_ = plswap(PB[5], PB[7]);                                      \
        B0.u[0] = (unsigned int)e0_[0]; B0.u[1] = (unsigned int)e1_[0];        \
        B0.u[2] = (unsigned int)e0_[1]; B0.u[3] = (unsigned int)e1_[1];        \
        B1.u[0] = (unsigned int)e2_[0]; B1.u[1] = (unsigned int)e3_[0];        \
        B1.u[2] = (unsigned int)e2_[1]; B1.u[3] = (unsigned int)e3_[1];        \
} while (0)
#else
#define EXCHANGE_P(PB, B0, B1) do {                                            \
        unsigned int qb_[8];                                                   \
        _Pragma("unroll")                                                      \
        for (int i_ = 0; i_ < 8; i_++)                                         \
            qb_[i_] = (unsigned int)__shfl_xor((int)PB[i_], 32);               \
        B0.u[0] = hi ? qb_[2] : PB[0]; B0.u[1] = hi ? qb_[3] : PB[1];          \
        B0.u[2] = hi ? PB[2] : qb_[0]; B0.u[3] = hi ? PB[3] : qb_[1];          \
        B1.u[0] = hi ? qb_[6] : PB[4]; B1.u[1] = hi ? qb_[7] : PB[5];          \
        B1.u[2] = hi ? PB[6] : qb_[4]; B1.u[3] = hi ? PB[7] : qb_[5];          \
} while (0)
#endif

// one tile-chain update; operands from coalesced fragment arrays (kbuf_/va_)
#define CORE(OT0, OT1, MR, LR, QH, BROW, kb_) do {                             \
        f32x16 st;                                                             \
        _Pragma("unroll")                                                      \
        for (int r_ = 0; r_ < 16; r_++) st[r_] = 0.f;                          \
        _Pragma("unroll")                                                      \
        for (int kc_ = 0; kc_ < 4; kc_++)                                      \
            st = mfma32(kbuf_[kc_], QH[kc_], st);                              \
        if ((kb_) == (BROW)) {                                                 \
            _Pragma("unroll")                                                  \
            for (int r_ = 0; r_ < 16; r_++) {                                  \
                int kvl_ = (r_ & 3) + 8 * (r_ >> 2) + 4 * hi;                  \
                if (kvl_ > l31) st[r_] = -1e30f;                               \
            }                                                                  \
        }                                                                      \
        float a0_ = fmaxf(fmaxf(st[0], st[1]), st[2]);                         \
        float a1_ = fmaxf(fmaxf(st[3], st[4]), st[5]);                         \
        float a2_ = fmaxf(fmaxf(st[6], st[7]), st[8]);                         \
        float a3_ = fmaxf(fmaxf(st[9], st[10]), st[11]);                       \
        float a4_ = fmaxf(fmaxf(st[12], st[13]), st[14]);                      \
        float b0m_ = fmaxf(fmaxf(a0_, a1_), a2_);                              \
        float b1m_ = fmaxf(fmaxf(a3_, a4_), st[15]);                           \
        float mx_ = xhalf_max(fmaxf(b0m_, b1m_));                              \
        if (__ballot(mx_ > MR + 11.0f)) {                                      \
            float mn_ = fmaxf(MR, mx_);                                        \
            float al_ = fexp2(MR - mn_);                                       \
            MR = mn_;                                                          \
            LR *= al_;                                                         \
            OT0 *= al_; OT1 *= al_;                                            \
        }                                                                      \
        _Pragma("unroll")                                                      \
        for (int r_ = 0; r_ < 16; r_++) st[r_] = fexp2(st[r_] - MR);           \
        {                                                                      \
            float s0 = (st[0] + st[1]) + (st[2] + st[3]);                      \
            float s1 = (st[4] + st[5]) + (st[6] + st[7]);                      \
            float s2 = (st[8] + st[9]) + (st[10] + st[11]);                    \
            float s3 = (st[12] + st[13]) + (st[14] + st[15]);                  \
            LR += ((s0 + s1) + (s2 + s3));                                     \
        }                                                                      \
        unsigned int pb_[8];                                                   \
        _Pragma("unroll")                                                      \
        for (int i_ = 0; i_ < 8; i_++) {                                       \
            PK pk_;                                                            \
            pk_.h = __builtin_amdgcn_cvt_pkrtz(st[2 * i_], st[2 * i_ + 1]);    \
            pb_[i_] = pk_.u;                                                   \
        }                                                                      \
        UB b0_, b1_;                                                           \
        EXCHANGE_P(pb_, b0_, b1_);                                             \
        OT0 = mfma32(va_[0][0], b0_.v, OT0);                                   \
        OT0 = mfma32(va_[0][1], b1_.v, OT0);                                   \
        OT1 = mfma32(va_[1][0], b0_.v, OT1);                                   \
        OT1 = mfma32(va_[1][1], b1_.v, OT1);                                   \
} while (0)

#define QLOAD(QH, q0_) do {                                                    \
        const float* qr_ = q_ptr + (size_t)((q0_) + l31) * Dc + hi * 8;        \
        _Pragma("unroll")                                                      \
        for (int kc_ = 0; kc_ < 4; kc_++) {                                    \
            f32x4 a_ = *(const f32x4*)(qr_ + kc_ * 16);                        \
            f32x4 b_ = *(const f32x4*)(qr_ + kc_ * 16 + 4);                    \
            float xs_[8] = {a_[0], a_[1], a_[2], a_[3], b_[0], b_[1], b_[2], b_[3]}; \
            _Pragma("unroll")                                                  \
            for (int j_ = 0; j_ < 8; j_++) QH[kc_][j_] = (f16_t)(xs_[j_] * LOG2E); \
        }                                                                      \
} while (0)

#define POST(OT0, OT1, MR, LS) do {                                            \
        _Pragma("unroll")                                                      \
        for (int r_ = 0; r_ < 16; r_++) {                                      \
            int d0_ = (r_ & 3) + 8 * (r_ >> 2) + 4 * hi;                       \
            lds_o[d0_ * 33 + l31]        = OT0[r_];                            \
            lds_o[(d0_ + 32) * 33 + l31] = OT1[r_];                            \
        }                                                                      \
        if (hi == 0) { lds_m[l31] = MR; lds_l[l31] = LS; }                     \
} while (0)

#define MERGE_WRITE(OT0, OT1, MR, LS, q0_) do {                                \
        float m1_ = lds_m[l31], l1_ = lds_l[l31];                              \
        float mm_ = fmaxf(MR, m1_);                                            \
        float c0_ = (MR  > -1e37f) ? fexp2(MR  - mm_) : 0.f;                   \
        float c1_ = (m1_ > -1e37f) ? fexp2(m1_ - mm_) : 0.f;                   \
        float lt_ = LS * c0_ + l1_ * c1_;                                      \
        float inv_ = (lt_ > 0.f) ? (1.f / lt_) : 0.f;                          \
        float* op_ = Out + bh_off + (size_t)((q0_) + l31) * Dc;                \
        _Pragma("unroll")                                                      \
        for (int g_ = 0; g_ < 4; g_++) {                                       \
            f32x4 w0_, w1_;                                                    \
            _Pragma("unroll")                                                  \
            for (int jj_ = 0; jj_ < 4; jj_++) {                                \
                int r_ = g_ * 4 + jj_;                                         \
                int d0_ = jj_ + 8 * g_ + 4 * hi;                               \
                w0_[jj_] = (OT0[r_] * c0_ + lds_o[d0_ * 33 + l31] * c1_) * inv_;        \
                w1_[jj_] = (OT1[r_] * c0_ + lds_o[(d0_ + 32) * 33 + l31] * c1_) * inv_; \
            }                                                                  \
            *(f32x4*)(op_ + g_ * 8 + hi * 4)      = w0_;                       \
            *(f32x4*)(op_ + 32 + g_ * 8 + hi * 4) = w1_;                       \
        }                                                                      \
} while (0)

__global__ __launch_bounds__(128, 2) void k_attn(const float* __restrict__ Q,
                                                 const f16_t* __restrict__ KHF,
                                                 const f16_t* __restrict__ VAF,
                                                 const unsigned char* __restrict__ BM,
                                                 float* __restrict__ Out) {
    __shared__ float lds_o[64 * 33];
    __shared__ float lds_m[32];
    __shared__ float lds_l[32];

    const int pair = blockIdx.x >> 5;              // 0..31
    const int bh   = blockIdx.x & 31;
    const int h    = bh & (Hc - 1);
    const int w    = threadIdx.x >> 6;
    const int lane = threadIdx.x & 63;
    const int l31  = lane & 31, hi = lane >> 5;

    const size_t bh_off = (size_t)bh * Sc * Dc;
    const float* q_ptr  = Q + bh_off;
    const f16_t* khfp   = KHF + (size_t)bh * FRAG_BH;
    const f16_t* vafp   = VAF + (size_t)bh * FRAG_BH;

    const int qiA = pair, qiB = 63 - pair;         // qiA <= 31 < qiB
    const unsigned char* bmA = BM + ((size_t)h * NB + qiA) * NB;
    const unsigned char* bmB = BM + ((size_t)h * NB + qiB) * NB;
    const unsigned long long amA = __ballot(bmA[lane] != 0);
    const unsigned long long amB = __ballot(bmB[lane] != 0);

    f16x8 qhA[4], qhB[4];
    QLOAD(qhA, qiA * 32);
    QLOAD(qhB, qiB * 32);

    f32x16 oA0, oA1, oB0, oB1;
#pragma unroll
    for (int r = 0; r < 16; r++) { oA0[r] = 0.f; oA1[r] = 0.f; oB0[r] = 0.f; oB1[r] = 0.f; }
    float mA = -INFINITY, lA = 0.f, mB = -INFINITY, lB = 0.f;

    // this wave handles kb == w (mod 2); all operand loads coalesced (base + lane*16B)
    for (int kb = w; kb <= qiB; kb += 2) {
        const bool aA = (kb <= qiA) && ((amA >> kb) & 1ull);
        const bool aB = (amB >> kb) & 1ull;
        if (!(aA || aB)) continue;
        f16x8 kbuf_[4];
#pragma unroll
        for (int kc = 0; kc < 4; kc++)
            kbuf_[kc] = *(const f16x8*)(khfp + (((size_t)kb * 4 + kc) * 64 + lane) * 8);
        f16x8 va_[2][2];
#pragma unroll
        for (int t = 0; t < 2; t++)
#pragma unroll
            for (int c = 0; c < 2; c++)
                va_[t][c] = *(const f16x8*)(vafp + (((size_t)kb * 4 + t * 2 + c) * 64 + lane) * 8);
        if (aA) CORE(oA0, oA1, mA, lA, qhA, qiA, kb);
        if (aB) CORE(oB0, oB1, mB, lB, qhB, qiB, kb);
    }

    const float lsA = xhalf_sum(lA);
    const float lsB = xhalf_sum(lB);

    // two-phase merge through one LDS buffer (epilogue only)
    if (w == 1) POST(oA0, oA1, mA, lsA);
    __syncthreads();
    if (w == 0) MERGE_WRITE(oA0, oA1, mA, lsA, qiA * 32);
    __syncthreads();
    if (w == 0) POST(oB0, oB1, mB, lsB);
    __syncthreads();
    if (w == 1) MERGE_WRITE(oB0, oB1, mB, lsB, qiB * 32);
}

extern "C" void kernel_launch(void* const* d_in, const int* in_sizes, int n_in,
                              void* d_out, int out_size, void* d_ws, size_t ws_size,
                              hipStream_t stream) {
    const float* Q    = (const float*)d_in[0];
    const float* K    = (const float*)d_in[1];
    const float* V    = (const float*)d_in[2];
    const float* bias = (const float*)d_in[3];
    const int*   mask = (const int*)d_in[4];
    float* out = (float*)d_out;

    char* ws = (char*)d_ws;
    f16_t* khf = (f16_t*)ws;                                    // 8 MiB
    f16_t* vaf = (f16_t*)(ws + (size_t)32 * FRAG_BH * 2);       // 8 MiB
    unsigned char* bm = (unsigned char*)(ws + (size_t)64 * FRAG_BH * 2);  // 64 KiB

    k_prep <<<5120, 256, 0, stream>>>(K, V, mask, bias, khf, vaf, bm);
    k_attn <<<Hc * Bc * (NB / 2), 128, 0, stream>>>(Q, khf, vaf, bm, out);
}